// Round 1
// 349.206 us; speedup vs baseline: 1.0630x; 1.0630x over previous
//
#include <hip/hip_runtime.h>

#define TWO_PI 6.283185307179586f

typedef _Float16 half8 __attribute__((ext_vector_type(8)));
typedef _Float16 half4 __attribute__((ext_vector_type(4)));
typedef float floatx4 __attribute__((ext_vector_type(4)));

// async global->LDS, 16B per lane. LDS dest = wave-uniform base + lane*16.
__device__ __forceinline__ void async16(const _Float16* g, _Float16* l) {
    __builtin_amdgcn_global_load_lds(
        (const __attribute__((address_space(1))) void*)g,
        (__attribute__((address_space(3))) void*)l, 16, 0, 0);
}

// ------------------------------------------------------------------
// prep_box body: per-batch proposal AABB/vol/semmask (256 thr) -> LDS ->
// box-query IoU argmax (threads 0..63). One block per batch.
// ------------------------------------------------------------------
__device__ __forceinline__ void prep_box_body(
    int b, const float* __restrict__ logits, const float* __restrict__ corners,
    const float* __restrict__ box_query, int* __restrict__ match_idx, float* sm)
{
    float* smn  = sm;          // [256][3]
    float* smx  = sm + 768;    // [256][3]
    float* svol = sm + 1536;   // [256]
    float* smsk = sm + 1792;   // [256]
    int t = threadIdx.x;
    {
        const float* c = corners + ((size_t)b*256 + t) * 24;
        float mn0 = c[0], mn1 = c[1], mn2 = c[2];
        float mx0 = mn0, mx1 = mn1, mx2 = mn2;
#pragma unroll
        for (int k = 1; k < 8; k++) {
            float v0 = c[k*3+0], v1 = c[k*3+1], v2 = c[k*3+2];
            mn0 = fminf(mn0, v0); mx0 = fmaxf(mx0, v0);
            mn1 = fminf(mn1, v1); mx1 = fmaxf(mx1, v1);
            mn2 = fminf(mn2, v2); mx2 = fmaxf(mx2, v2);
        }
        smn[t*3+0] = mn0; smn[t*3+1] = mn1; smn[t*3+2] = mn2;
        smx[t*3+0] = mx0; smx[t*3+1] = mx1; smx[t*3+2] = mx2;
        svol[t] = (mx0-mn0)*(mx1-mn1)*(mx2-mn2);
        const float* lg = logits + ((size_t)b*256 + t) * 19;
        float bv = lg[0]; int bi = 0;
#pragma unroll
        for (int k = 1; k < 19; k++) { float v = lg[k]; if (v > bv) { bv = v; bi = k; } }
        smsk[t] = (bi != 18) ? 1.0f : 0.0f;
    }
    __syncthreads();
    if (t < 64) {
        int gq = b*64 + t;
        const float* cq = box_query + (size_t)gq * 24;
        float mn0 = cq[0], mn1 = cq[1], mn2 = cq[2];
        float mx0 = mn0, mx1 = mn1, mx2 = mn2;
#pragma unroll
        for (int k = 1; k < 8; k++) {
            float v0 = cq[k*3+0], v1 = cq[k*3+1], v2 = cq[k*3+2];
            mn0 = fminf(mn0, v0); mx0 = fmaxf(mx0, v0);
            mn1 = fminf(mn1, v1); mx1 = fmaxf(mx1, v1);
            mn2 = fminf(mn2, v2); mx2 = fmaxf(mx2, v2);
        }
        float volq = (mx0-mn0)*(mx1-mn1)*(mx2-mn2);
        float best = -1.0f; int bi = 0;
        for (int p = 0; p < 256; p++) {
            float e0 = fminf(mx0, smx[p*3+0]) - fmaxf(mn0, smn[p*3+0]); e0 = fmaxf(e0, 0.0f);
            float e1 = fminf(mx1, smx[p*3+1]) - fmaxf(mn1, smn[p*3+1]); e1 = fmaxf(e1, 0.0f);
            float e2 = fminf(mx2, smx[p*3+2]) - fmaxf(mn2, smn[p*3+2]); e2 = fmaxf(e2, 0.0f);
            float inter = (e0*e1)*e2;
            float iou = inter / (volq + svol[p] - inter + 1e-8f) * smsk[p];
            if (iou > best) { best = iou; bi = p; }   // strict > keeps first
        }
        match_idx[gq] = bi;
    }
}

// ------------------------------------------------------------------
// Transpose+convert core: src fp32 [K][N] -> dst f16 [N][K], 64x64 tile
// ------------------------------------------------------------------
__device__ __forceinline__ void transpose_core(
    const float* __restrict__ src, _Float16* __restrict__ dst,
    int K, int N, _Float16* t, int bx, int by)
{
    int n0 = bx * 64, k0 = by * 64;
    int tid = threadIdx.x;          // 256
    int r = tid >> 4;               // 0..15
    int c4 = (tid & 15) * 4;
#pragma unroll
    for (int p = 0; p < 4; p++) {
        int k = r + p*16;
        float4 v = *(const float4*)(src + (size_t)(k0+k)*N + n0 + c4);
        t[(c4+0)*68 + k] = (_Float16)v.x;
        t[(c4+1)*68 + k] = (_Float16)v.y;
        t[(c4+2)*68 + k] = (_Float16)v.z;
        t[(c4+3)*68 + k] = (_Float16)v.w;
    }
    __syncthreads();
    int ck = (tid & 15) * 4;
#pragma unroll
    for (int p = 0; p < 4; p++) {
        int n = r + p*16;
        half4 v = *(const half4*)(t + n*68 + ck);
        *(half4*)(dst + (size_t)(n0+n)*K + k0 + ck) = v;
    }
}

// ------------------------------------------------------------------
// Fused prep kernel: [0,2304) transpose_w2 | [2304,2496) transpose_w1 |
//                    [2496,2528) prep_box.  All branches block-uniform.
// ------------------------------------------------------------------
__global__ void prep_fused(
    const float* __restrict__ logits, const float* __restrict__ corners,
    const float* __restrict__ box_query, int* __restrict__ match_idx,
    const float* __restrict__ bw1, const float* __restrict__ cw1,
    _Float16* __restrict__ w1t_box, _Float16* __restrict__ w1t_clk,
    const float* __restrict__ bw2, const float* __restrict__ cw2,
    _Float16* __restrict__ w2t_box, _Float16* __restrict__ w2t_clk)
{
    __shared__ float smem[2176];            // 8704 B: max(prep 8192, transpose 8704)
    int bid = blockIdx.x;
    if (bid < 2304) {
        // transpose_w2: 768x6144 -> 6144x768, grid (96,12,2)
        _Float16* tb = (_Float16*)smem;
        int x = bid % 96, y = (bid / 96) % 12, z = bid / 1152;
        if (z == 0) transpose_core(bw2, w2t_box, 768, 6144, tb, x, y);
        else        transpose_core(cw2, w2t_clk, 768, 6144, tb, x, y);
    } else if (bid < 2496) {
        // transpose_w1: grid (12,8,2); box branch only y<4 (K=256)
        _Float16* tb = (_Float16*)smem;
        int r = bid - 2304;
        int x = r % 12, y = (r / 12) % 8, z = r / 96;
        if (z == 0) {
            if (y < 4) transpose_core(bw1, w1t_box, 256, 768, tb, x, y);
        } else {
            transpose_core(cw1, w1t_clk, 512, 768, tb, x, y);
        }
    } else {
        prep_box_body(bid - 2496, logits, corners, box_query, match_idx, smem);
    }
}

// ------------------------------------------------------------------
// Fused: block-parallel click NN argmin (first-min tiebreak) +
//        gather box/click feats + fourier pos embed + prompt mask.
// One block per row (2048 rows).
// ------------------------------------------------------------------
__global__ void gather_nn(const float* __restrict__ prop_features,
                          const float* __restrict__ enc_features,
                          const float* __restrict__ enc_xyz,
                          const int* __restrict__ match_idx,
                          const float* __restrict__ cq,
                          const float* __restrict__ pc_min,
                          const float* __restrict__ pc_max,
                          const float* __restrict__ gB,
                          const float* __restrict__ box_qmask,
                          const float* __restrict__ click_qmask,
                          _Float16* __restrict__ box_in,
                          _Float16* __restrict__ click_in,
                          float* __restrict__ out)
{
    __shared__ float rd[4];
    __shared__ int   ri[4];
    __shared__ int   s_nn;
    int row = blockIdx.x;     // 2048
    int t = threadIdx.x;      // 256
    int b = row >> 6;
    int lane = t & 63, wave = t >> 6;

    // ---- click NN over 4096 points, 16 pts/thread ----
    float cx = cq[row*3+0];
    float cy = cq[row*3+1];
    float cz = cq[row*3+2];
    const float* ex = enc_xyz + (size_t)b * 4096 * 3;
    float best = 3.4e38f; int bidx = 0;
#pragma unroll
    for (int i = 0; i < 16; i++) {
        int p = t + i*256;
        float dx = cx - ex[p*3+0];
        float dy = cy - ex[p*3+1];
        float dz = cz - ex[p*3+2];
        float d = dx*dx + dy*dy;
        d = d + dz*dz;
        if (d < best) { best = d; bidx = p; }   // strict <, p ascending -> first min
    }
#pragma unroll
    for (int off = 32; off; off >>= 1) {
        float ov = __shfl_down(best, off);
        int   oi = __shfl_down(bidx, off);
        if (ov < best || (ov == best && oi < bidx)) { best = ov; bidx = oi; }
    }
    if (lane == 0) { rd[wave] = best; ri[wave] = bidx; }
    __syncthreads();
    if (t == 0) {
        float bv = rd[0]; int bi = ri[0];
#pragma unroll
        for (int w = 1; w < 4; w++) {
            if (rd[w] < bv || (rd[w] == bv && ri[w] < bi)) { bv = rd[w]; bi = ri[w]; }
        }
        s_nn = bi;
    }
    __syncthreads();
    int nnid = s_nn;

    // ---- gathers + fourier pos embed ----
    box_in[(size_t)row*256 + t] =
        (_Float16)prop_features[((size_t)b*256 + match_idx[row])*256 + t];
    click_in[(size_t)row*512 + t] =
        (_Float16)enc_features[((size_t)b*4096 + nnid)*256 + t];
    int j = t & 127;
    float m0 = pc_min[b*3+0], m1 = pc_min[b*3+1], m2 = pc_min[b*3+2];
    float tx = (cx - m0) / (pc_max[b*3+0] - m0) * TWO_PI;
    float ty = (cy - m1) / (pc_max[b*3+1] - m1) * TWO_PI;
    float tz = (cz - m2) / (pc_max[b*3+2] - m2) * TWO_PI;
    float p = tx * gB[j] + ty * gB[128+j] + tz * gB[256+j];
    float v = (t < 128) ? sinf(p) : cosf(p);
    click_in[(size_t)row*512 + 256 + t] = (_Float16)v;
    // prompt mask: 16 elements per row-block
    if (t < 16) {
        int idx = row*16 + t;            // 0..32767
        int mb = idx >> 10, i = idx & 1023;
        float mv = (i < 512) ? box_qmask[mb*64 + (i >> 3)]
                             : click_qmask[mb*64 + ((i - 512) >> 3)];
        out[25165824 + idx] = mv;
    }
}

// ------------------------------------------------------------------
// f16 MFMA GEMM core: C[M,N] = A[M,K] @ Bt[N,K]^T + bias
// 128x128 tile, BK=64, XOR-swizzled LDS (conflict-free ds_read_b128),
// global_load_lds width-16 staging. K % 64 == 0.
// MODE 0: relu -> f16 Hout (row-major, stride N)
// MODE 1: fp32 -> Fout, prompt reshape: off=(m>>6)*786432+brOff+(m&63)*6144+n
// ------------------------------------------------------------------
template<int MODE>
__device__ __forceinline__ void gemm_core(
    const _Float16* __restrict__ A, const _Float16* __restrict__ Bt,
    const float* __restrict__ bias, int N, int K,
    _Float16* __restrict__ Hout, float* __restrict__ Fout, long brOff,
    int bm, int bn, _Float16* As, _Float16* Bs)
{
    const int tid = threadIdx.x;
    const int wave = tid >> 6, lane = tid & 63;
    const int waveM = (wave & 1) * 64, waveN = (wave >> 1) * 64;
    const int nrow = lane & 15;         // fragment row within 16
    const int kq   = lane >> 4;         // fragment k quarter (0..3)

    // staging: thread -> (row = q*32 + (tid>>3), jslot = tid&7),
    // fetches global data k-block jdata = jslot ^ (row&7)
    const int srow = tid >> 3;                                  // 0..31
    const int jdat = ((tid & 7) ^ (srow & 7)) * 8;              // half offset

    floatx4 acc[4][4];
#pragma unroll
    for (int i = 0; i < 4; i++)
#pragma unroll
        for (int j = 0; j < 4; j++) { floatx4 z = {0.f,0.f,0.f,0.f}; acc[i][j] = z; }

    const _Float16* Ab[4]; const _Float16* Bb[4];
    _Float16 *lA[4], *lB[4];
#pragma unroll
    for (int q = 0; q < 4; q++) {
        Ab[q] = A  + (size_t)(bm*128 + q*32 + srow) * K + jdat;
        Bb[q] = Bt + (size_t)(bn*128 + q*32 + srow) * K + jdat;
        lA[q] = As + q*2048 + wave*512;
        lB[q] = Bs + q*2048 + wave*512;
    }

    for (int kk = 0; kk < K; kk += 64) {
        __syncthreads();                 // prior-tile LDS reads done
#pragma unroll
        for (int q = 0; q < 4; q++) async16(Ab[q] + kk, lA[q]);
#pragma unroll
        for (int q = 0; q < 4; q++) async16(Bb[q] + kk, lB[q]);
        __syncthreads();                 // staging complete
#pragma unroll
        for (int h = 0; h < 2; h++) {
            const int sw = (((kq + h*4) ^ (nrow & 7)) * 8);
            half8 af[4], bf[4];
#pragma unroll
            for (int i = 0; i < 4; i++)
                af[i] = *(const half8*)(As + (waveM + i*16 + nrow)*64 + sw);
#pragma unroll
            for (int j = 0; j < 4; j++)
                bf[j] = *(const half8*)(Bs + (waveN + j*16 + nrow)*64 + sw);
#pragma unroll
            for (int i = 0; i < 4; i++)
#pragma unroll
                for (int j = 0; j < 4; j++)
                    acc[i][j] = __builtin_amdgcn_mfma_f32_16x16x32_f16(af[i], bf[j], acc[i][j], 0, 0, 0);
        }
    }

    // epilogue: C/D layout col = lane&15, row = (lane>>4)*4 + reg
#pragma unroll
    for (int i = 0; i < 4; i++) {
#pragma unroll
        for (int j = 0; j < 4; j++) {
            int col = bn*128 + waveN + j*16 + nrow;
            float bv = bias[col];
#pragma unroll
            for (int r = 0; r < 4; r++) {
                int row = bm*128 + waveM + i*16 + kq*4 + r;
                float v = acc[i][j][r] + bv;
                if (MODE == 0) {
                    v = v > 0.f ? v : 0.f;
                    Hout[(size_t)row * N + col] = (_Float16)v;
                } else {
                    size_t off = (size_t)(row >> 6) * 786432 + (size_t)brOff
                               + (size_t)(row & 63) * 6144 + col;
                    Fout[off] = v;
                }
            }
        }
    }
}

// layer-1: both branches (z: 0=box K=256, 1=click K=512), N=768
__global__ __launch_bounds__(256) void gemm_l1(
    const _Float16* __restrict__ A0, const _Float16* __restrict__ A1,
    const _Float16* __restrict__ B0, const _Float16* __restrict__ B1,
    const float* __restrict__ b0, const float* __restrict__ b1,
    _Float16* __restrict__ H0, _Float16* __restrict__ H1)
{
    __shared__ _Float16 As[8192];
    __shared__ _Float16 Bs[8192];
    if (blockIdx.z == 0)
        gemm_core<0>(A0, B0, b0, 768, 256, H0, nullptr, 0,
                     blockIdx.x, blockIdx.y, As, Bs);
    else
        gemm_core<0>(A1, B1, b1, 768, 512, H1, nullptr, 0,
                     blockIdx.x, blockIdx.y, As, Bs);
}

// layer-2: both branches (z: 0=box, 1=click), N=6144, K=768
// XCD-aware remap: 768 blocks/branch; each XCD (lin%8) gets a contiguous
// bn range of 6 tiles -> per-XCD L2 holds full A panel (3MB) + B slice (1.2MB)
__global__ __launch_bounds__(256) void gemm_l2(
    const _Float16* __restrict__ A0, const _Float16* __restrict__ A1,
    const _Float16* __restrict__ B0, const _Float16* __restrict__ B1,
    const float* __restrict__ b0, const float* __restrict__ b1,
    float* __restrict__ out)
{
    __shared__ _Float16 As[8192];
    __shared__ _Float16 Bs[8192];
    int lin = blockIdx.x + 16 * blockIdx.y;   // 0..767
    int xcd = lin & 7;
    int per = lin >> 3;                        // 0..95
    int bm  = per & 15;                        // 0..15  (per%16)
    int bn  = xcd * 6 + (per >> 4);            // 0..47  (bijective: 48%8==0)
    if (blockIdx.z == 0)
        gemm_core<1>(A0, B0, b0, 6144, 768, nullptr, out, 0,      bm, bn, As, Bs);
    else
        gemm_core<1>(A1, B1, b1, 6144, 768, nullptr, out, 393216, bm, bn, As, Bs);
}

// ------------------------------------------------------------------
extern "C" void kernel_launch(void* const* d_in, const int* in_sizes, int n_in,
                              void* d_out, int out_size, void* d_ws, size_t ws_size,
                              hipStream_t stream)
{
    const float* sem   = (const float*)d_in[0];
    const float* propf = (const float*)d_in[1];
    const float* boxc  = (const float*)d_in[2];
    const float* encx  = (const float*)d_in[3];
    const float* encf  = (const float*)d_in[4];
    const float* pcmin = (const float*)d_in[5];
    const float* pcmax = (const float*)d_in[6];
    const float* boxq  = (const float*)d_in[7];
    const float* boxm  = (const float*)d_in[8];
    const float* clkq  = (const float*)d_in[9];
    const float* clkm  = (const float*)d_in[10];
    const float* gB    = (const float*)d_in[11];
    const float* bw1   = (const float*)d_in[12];
    const float* bb1   = (const float*)d_in[13];
    const float* bw2   = (const float*)d_in[14];
    const float* bb2   = (const float*)d_in[15];
    const float* cw1   = (const float*)d_in[16];
    const float* cb1   = (const float*)d_in[17];
    const float* cw2   = (const float*)d_in[18];
    const float* cb2   = (const float*)d_in[19];
    float* out = (float*)d_out;
    char* ws = (char*)d_ws;

    int* midx    = (int*)(ws + 262144);
    _Float16* box_in   = (_Float16*)(ws + 278528);    // 2048x256
    _Float16* click_in = (_Float16*)(ws + 1327104);   // 2048x512
    _Float16* h_box    = (_Float16*)(ws + 3424256);   // 2048x768
    _Float16* h_click  = (_Float16*)(ws + 6569984);   // 2048x768
    _Float16* w1t_box  = (_Float16*)(ws + 9715712);   // 768x256
    _Float16* w2t_box  = (_Float16*)(ws + 10108928);  // 6144x768
    _Float16* w1t_clk  = (_Float16*)(ws + 19546112);  // 768x512
    _Float16* w2t_clk  = (_Float16*)(ws + 20332544);  // 6144x768

    // K1: prep_box + both weight transposes (independent work, one launch)
    prep_fused<<<2528, 256, 0, stream>>>(sem, boxc, boxq, midx,
                                         bw1, cw1, w1t_box, w1t_clk,
                                         bw2, cw2, w2t_box, w2t_clk);
    // K2: click NN + gathers + pos-embed + mask
    gather_nn<<<2048, 256, 0, stream>>>(propf, encf, encx, midx, clkq,
                                        pcmin, pcmax, gB, boxm, clkm,
                                        box_in, click_in, out);
    // K3/K4: MLP GEMMs
    gemm_l1<<<dim3(16, 6, 2),  256, 0, stream>>>(box_in, click_in, w1t_box, w1t_clk,
                                                 bb1, cb1, h_box, h_click);
    gemm_l2<<<dim3(16, 48, 2), 256, 0, stream>>>(h_box, h_click, w2t_box, w2t_clk,
                                                 bb2, cb2, out);
}

// Round 2
// 322.451 us; speedup vs baseline: 1.1512x; 1.0830x over previous
//
#include <hip/hip_runtime.h>

#define TWO_PI 6.283185307179586f

typedef _Float16 half8 __attribute__((ext_vector_type(8)));
typedef _Float16 half4 __attribute__((ext_vector_type(4)));
typedef float floatx4 __attribute__((ext_vector_type(4)));

// async global->LDS, 16B per lane. LDS dest = wave-uniform base + lane*16.
__device__ __forceinline__ void async16(const _Float16* g, _Float16* l) {
    __builtin_amdgcn_global_load_lds(
        (const __attribute__((address_space(1))) void*)g,
        (__attribute__((address_space(3))) void*)l, 16, 0, 0);
}

// ------------------------------------------------------------------
// Transpose+convert core: src fp32 [K][N] -> dst f16 [N][K], 64x64 tile
// ------------------------------------------------------------------
__device__ __forceinline__ void transpose_core(
    const float* __restrict__ src, _Float16* __restrict__ dst,
    int K, int N, _Float16* t, int bx, int by)
{
    int n0 = bx * 64, k0 = by * 64;
    int tid = threadIdx.x;          // 256
    int r = tid >> 4;               // 0..15
    int c4 = (tid & 15) * 4;
#pragma unroll
    for (int p = 0; p < 4; p++) {
        int k = r + p*16;
        float4 v = *(const float4*)(src + (size_t)(k0+k)*N + n0 + c4);
        t[(c4+0)*68 + k] = (_Float16)v.x;
        t[(c4+1)*68 + k] = (_Float16)v.y;
        t[(c4+2)*68 + k] = (_Float16)v.z;
        t[(c4+3)*68 + k] = (_Float16)v.w;
    }
    __syncthreads();
    int ck = (tid & 15) * 4;
#pragma unroll
    for (int p = 0; p < 4; p++) {
        int n = r + p*16;
        half4 v = *(const half4*)(t + n*68 + ck);
        *(half4*)(dst + (size_t)(n0+n)*K + k0 + ck) = v;
    }
}

// ------------------------------------------------------------------
// Mega prep kernel (single launch, no inter-block deps):
//   [0,2304)    transpose_w2 (768x6144 -> 6144x768, both branches)
//   [2304,2496) transpose_w1 (box K=256 / click K=512)
//   [2496,4544) per-row blocks (2048): box IoU-argmax match (1 proposal
//               per thread, block argmax reduce, first-max tiebreak) +
//               click NN argmin (16 pts/thread, first-min tiebreak) +
//               feature gathers + fourier pos embed + prompt mask.
// ------------------------------------------------------------------
__global__ void mega_prep(
    const float* __restrict__ logits, const float* __restrict__ corners,
    const float* __restrict__ box_query,
    const float* __restrict__ bw1, const float* __restrict__ cw1,
    _Float16* __restrict__ w1t_box, _Float16* __restrict__ w1t_clk,
    const float* __restrict__ bw2, const float* __restrict__ cw2,
    _Float16* __restrict__ w2t_box, _Float16* __restrict__ w2t_clk,
    const float* __restrict__ prop_features,
    const float* __restrict__ enc_features,
    const float* __restrict__ enc_xyz,
    const float* __restrict__ cq,
    const float* __restrict__ pc_min,
    const float* __restrict__ pc_max,
    const float* __restrict__ gB,
    const float* __restrict__ box_qmask,
    const float* __restrict__ click_qmask,
    _Float16* __restrict__ box_in,
    _Float16* __restrict__ click_in,
    float* __restrict__ out)
{
    __shared__ float smem[2176];            // 8704 B transpose tile
    __shared__ float nnd[4]; __shared__ int nni[4];
    __shared__ float bxd[4]; __shared__ int bxi[4];
    __shared__ int s_nn, s_match;
    int bid = blockIdx.x;
    if (bid < 2304) {
        // transpose_w2: grid (96,12,2)
        _Float16* tb = (_Float16*)smem;
        int x = bid % 96, y = (bid / 96) % 12, z = bid / 1152;
        if (z == 0) transpose_core(bw2, w2t_box, 768, 6144, tb, x, y);
        else        transpose_core(cw2, w2t_clk, 768, 6144, tb, x, y);
        return;
    }
    if (bid < 2496) {
        // transpose_w1: grid (12,8,2); box branch only y<4 (K=256)
        _Float16* tb = (_Float16*)smem;
        int r = bid - 2304;
        int x = r % 12, y = (r / 12) % 8, z = r / 96;
        if (z == 0) {
            if (y < 4) transpose_core(bw1, w1t_box, 256, 768, tb, x, y);
        } else {
            transpose_core(cw1, w1t_clk, 512, 768, tb, x, y);
        }
        return;
    }

    // ---------------- per-row block ----------------
    int row = bid - 2496;     // 0..2047  (== b*64 + q)
    int t = threadIdx.x;      // 256
    int b = row >> 6;
    int lane = t & 63, wave = t >> 6;

    // ---- click NN over 4096 points, 16 pts/thread ----
    float cx = cq[row*3+0];
    float cy = cq[row*3+1];
    float cz = cq[row*3+2];
    const float* ex = enc_xyz + (size_t)b * 4096 * 3;
    float nbest = 3.4e38f; int nbidx = 0;
#pragma unroll
    for (int i = 0; i < 16; i++) {
        int p = t + i*256;
        float dx = cx - ex[p*3+0];
        float dy = cy - ex[p*3+1];
        float dz = cz - ex[p*3+2];
        float d = dx*dx + dy*dy;
        d = d + dz*dz;
        if (d < nbest) { nbest = d; nbidx = p; }   // strict <, p ascending -> first min
    }
#pragma unroll
    for (int off = 32; off; off >>= 1) {
        float ov = __shfl_down(nbest, off);
        int   oi = __shfl_down(nbidx, off);
        if (ov < nbest || (ov == nbest && oi < nbidx)) { nbest = ov; nbidx = oi; }
    }
    if (lane == 0) { nnd[wave] = nbest; nni[wave] = nbidx; }

    // ---- box match: this thread owns proposal p = t ----
    float iou; int pidx = t;
    {
        const float* c = corners + ((size_t)b*256 + t) * 24;
        float mn0 = c[0], mn1 = c[1], mn2 = c[2];
        float mx0 = mn0, mx1 = mn1, mx2 = mn2;
#pragma unroll
        for (int k = 1; k < 8; k++) {
            float v0 = c[k*3+0], v1 = c[k*3+1], v2 = c[k*3+2];
            mn0 = fminf(mn0, v0); mx0 = fmaxf(mx0, v0);
            mn1 = fminf(mn1, v1); mx1 = fmaxf(mx1, v1);
            mn2 = fminf(mn2, v2); mx2 = fmaxf(mx2, v2);
        }
        float pvol = (mx0-mn0)*(mx1-mn1)*(mx2-mn2);
        const float* lg = logits + ((size_t)b*256 + t) * 19;
        float bv = lg[0]; int bi = 0;
#pragma unroll
        for (int k = 1; k < 19; k++) { float v = lg[k]; if (v > bv) { bv = v; bi = k; } }
        float pmsk = (bi != 18) ? 1.0f : 0.0f;

        // query AABB (same for all threads in block)
        const float* qc = box_query + (size_t)row * 24;
        float qn0 = qc[0], qn1 = qc[1], qn2 = qc[2];
        float qx0 = qn0, qx1 = qn1, qx2 = qn2;
#pragma unroll
        for (int k = 1; k < 8; k++) {
            float v0 = qc[k*3+0], v1 = qc[k*3+1], v2 = qc[k*3+2];
            qn0 = fminf(qn0, v0); qx0 = fmaxf(qx0, v0);
            qn1 = fminf(qn1, v1); qx1 = fmaxf(qx1, v1);
            qn2 = fminf(qn2, v2); qx2 = fmaxf(qx2, v2);
        }
        float qvol = (qx0-qn0)*(qx1-qn1)*(qx2-qn2);
        float e0 = fminf(qx0, mx0) - fmaxf(qn0, mn0); e0 = fmaxf(e0, 0.0f);
        float e1 = fminf(qx1, mx1) - fmaxf(qn1, mn1); e1 = fmaxf(e1, 0.0f);
        float e2 = fminf(qx2, mx2) - fmaxf(qn2, mn2); e2 = fmaxf(e2, 0.0f);
        float inter = (e0*e1)*e2;
        iou = inter / (qvol + pvol - inter + 1e-8f) * pmsk;
    }
#pragma unroll
    for (int off = 32; off; off >>= 1) {
        float ov = __shfl_down(iou, off);
        int   oi = __shfl_down(pidx, off);
        if (ov > iou || (ov == iou && oi < pidx)) { iou = ov; pidx = oi; }
    }
    if (lane == 0) { bxd[wave] = iou; bxi[wave] = pidx; }
    __syncthreads();
    if (t == 0) {
        float nv = nnd[0]; int ni = nni[0];
        float bv = bxd[0]; int bi = bxi[0];
#pragma unroll
        for (int w = 1; w < 4; w++) {
            if (nnd[w] < nv || (nnd[w] == nv && nni[w] < ni)) { nv = nnd[w]; ni = nni[w]; }
            if (bxd[w] > bv || (bxd[w] == bv && bxi[w] < bi)) { bv = bxd[w]; bi = bxi[w]; }
        }
        s_nn = ni; s_match = bi;
    }
    __syncthreads();
    int nnid = s_nn, match = s_match;

    // ---- gathers + fourier pos embed ----
    box_in[(size_t)row*256 + t] =
        (_Float16)prop_features[((size_t)b*256 + match)*256 + t];
    click_in[(size_t)row*512 + t] =
        (_Float16)enc_features[((size_t)b*4096 + nnid)*256 + t];
    int j = t & 127;
    float m0 = pc_min[b*3+0], m1 = pc_min[b*3+1], m2 = pc_min[b*3+2];
    float tx = (cx - m0) / (pc_max[b*3+0] - m0) * TWO_PI;
    float ty = (cy - m1) / (pc_max[b*3+1] - m1) * TWO_PI;
    float tz = (cz - m2) / (pc_max[b*3+2] - m2) * TWO_PI;
    float p = tx * gB[j] + ty * gB[128+j] + tz * gB[256+j];
    float v = (t < 128) ? sinf(p) : cosf(p);
    click_in[(size_t)row*512 + 256 + t] = (_Float16)v;
    // prompt mask: 16 elements per row-block
    if (t < 16) {
        int idx = row*16 + t;            // 0..32767
        int mb = idx >> 10, i = idx & 1023;
        float mv = (i < 512) ? box_qmask[mb*64 + (i >> 3)]
                             : click_qmask[mb*64 + ((i - 512) >> 3)];
        out[25165824 + idx] = mv;
    }
}

// ------------------------------------------------------------------
// f16 MFMA GEMM core: C[M,N] = A[M,K] @ Bt[N,K]^T + bias
// 128x128 tile, BK=64, XOR-swizzled LDS (conflict-free ds_read_b128),
// global_load_lds width-16 staging. K % 64 == 0.
// MODE 0: relu -> f16 Hout (row-major, stride N)
// MODE 1: fp32 -> Fout, prompt reshape: off=(m>>6)*786432+brOff+(m&63)*6144+n
// ------------------------------------------------------------------
template<int MODE>
__device__ __forceinline__ void gemm_core(
    const _Float16* __restrict__ A, const _Float16* __restrict__ Bt,
    const float* __restrict__ bias, int N, int K,
    _Float16* __restrict__ Hout, float* __restrict__ Fout, long brOff,
    int bm, int bn, _Float16* As, _Float16* Bs)
{
    const int tid = threadIdx.x;
    const int wave = tid >> 6, lane = tid & 63;
    const int waveM = (wave & 1) * 64, waveN = (wave >> 1) * 64;
    const int nrow = lane & 15;         // fragment row within 16
    const int kq   = lane >> 4;         // fragment k quarter (0..3)

    // staging: thread -> (row = q*32 + (tid>>3), jslot = tid&7),
    // fetches global data k-block jdata = jslot ^ (row&7)
    const int srow = tid >> 3;                                  // 0..31
    const int jdat = ((tid & 7) ^ (srow & 7)) * 8;              // half offset

    floatx4 acc[4][4];
#pragma unroll
    for (int i = 0; i < 4; i++)
#pragma unroll
        for (int j = 0; j < 4; j++) { floatx4 z = {0.f,0.f,0.f,0.f}; acc[i][j] = z; }

    const _Float16* Ab[4]; const _Float16* Bb[4];
    _Float16 *lA[4], *lB[4];
#pragma unroll
    for (int q = 0; q < 4; q++) {
        Ab[q] = A  + (size_t)(bm*128 + q*32 + srow) * K + jdat;
        Bb[q] = Bt + (size_t)(bn*128 + q*32 + srow) * K + jdat;
        lA[q] = As + q*2048 + wave*512;
        lB[q] = Bs + q*2048 + wave*512;
    }

    for (int kk = 0; kk < K; kk += 64) {
        __syncthreads();                 // prior-tile LDS reads done
#pragma unroll
        for (int q = 0; q < 4; q++) async16(Ab[q] + kk, lA[q]);
#pragma unroll
        for (int q = 0; q < 4; q++) async16(Bb[q] + kk, lB[q]);
        __syncthreads();                 // staging complete
#pragma unroll
        for (int h = 0; h < 2; h++) {
            const int sw = (((kq + h*4) ^ (nrow & 7)) * 8);
            half8 af[4], bf[4];
#pragma unroll
            for (int i = 0; i < 4; i++)
                af[i] = *(const half8*)(As + (waveM + i*16 + nrow)*64 + sw);
#pragma unroll
            for (int j = 0; j < 4; j++)
                bf[j] = *(const half8*)(Bs + (waveN + j*16 + nrow)*64 + sw);
#pragma unroll
            for (int i = 0; i < 4; i++)
#pragma unroll
                for (int j = 0; j < 4; j++)
                    acc[i][j] = __builtin_amdgcn_mfma_f32_16x16x32_f16(af[i], bf[j], acc[i][j], 0, 0, 0);
        }
    }

    // epilogue: C/D layout col = lane&15, row = (lane>>4)*4 + reg
#pragma unroll
    for (int i = 0; i < 4; i++) {
#pragma unroll
        for (int j = 0; j < 4; j++) {
            int col = bn*128 + waveN + j*16 + nrow;
            float bv = bias[col];
#pragma unroll
            for (int r = 0; r < 4; r++) {
                int row = bm*128 + waveM + i*16 + kq*4 + r;
                float v = acc[i][j][r] + bv;
                if (MODE == 0) {
                    v = v > 0.f ? v : 0.f;
                    Hout[(size_t)row * N + col] = (_Float16)v;
                } else {
                    size_t off = (size_t)(row >> 6) * 786432 + (size_t)brOff
                               + (size_t)(row & 63) * 6144 + col;
                    Fout[off] = v;
                }
            }
        }
    }
}

// layer-1: both branches (z: 0=box K=256, 1=click K=512), N=768
__global__ __launch_bounds__(256) void gemm_l1(
    const _Float16* __restrict__ A0, const _Float16* __restrict__ A1,
    const _Float16* __restrict__ B0, const _Float16* __restrict__ B1,
    const float* __restrict__ b0, const float* __restrict__ b1,
    _Float16* __restrict__ H0, _Float16* __restrict__ H1)
{
    __shared__ _Float16 As[8192];
    __shared__ _Float16 Bs[8192];
    if (blockIdx.z == 0)
        gemm_core<0>(A0, B0, b0, 768, 256, H0, nullptr, 0,
                     blockIdx.x, blockIdx.y, As, Bs);
    else
        gemm_core<0>(A1, B1, b1, 768, 512, H1, nullptr, 0,
                     blockIdx.x, blockIdx.y, As, Bs);
}

// layer-2: both branches (z: 0=box, 1=click), N=6144, K=768
// XCD-aware remap: 768 blocks/branch; each XCD (lin%8) gets a contiguous
// bn range of 6 tiles -> per-XCD L2 holds full A panel (3MB) + B slice (1.2MB)
__global__ __launch_bounds__(256) void gemm_l2(
    const _Float16* __restrict__ A0, const _Float16* __restrict__ A1,
    const _Float16* __restrict__ B0, const _Float16* __restrict__ B1,
    const float* __restrict__ b0, const float* __restrict__ b1,
    float* __restrict__ out)
{
    __shared__ _Float16 As[8192];
    __shared__ _Float16 Bs[8192];
    int lin = blockIdx.x + 16 * blockIdx.y;   // 0..767
    int xcd = lin & 7;
    int per = lin >> 3;                        // 0..95
    int bm  = per & 15;                        // 0..15  (per%16)
    int bn  = xcd * 6 + (per >> 4);            // 0..47  (bijective: 48%8==0)
    if (blockIdx.z == 0)
        gemm_core<1>(A0, B0, b0, 6144, 768, nullptr, out, 0,      bm, bn, As, Bs);
    else
        gemm_core<1>(A1, B1, b1, 6144, 768, nullptr, out, 393216, bm, bn, As, Bs);
}

// ------------------------------------------------------------------
extern "C" void kernel_launch(void* const* d_in, const int* in_sizes, int n_in,
                              void* d_out, int out_size, void* d_ws, size_t ws_size,
                              hipStream_t stream)
{
    const float* sem   = (const float*)d_in[0];
    const float* propf = (const float*)d_in[1];
    const float* boxc  = (const float*)d_in[2];
    const float* encx  = (const float*)d_in[3];
    const float* encf  = (const float*)d_in[4];
    const float* pcmin = (const float*)d_in[5];
    const float* pcmax = (const float*)d_in[6];
    const float* boxq  = (const float*)d_in[7];
    const float* boxm  = (const float*)d_in[8];
    const float* clkq  = (const float*)d_in[9];
    const float* clkm  = (const float*)d_in[10];
    const float* gB    = (const float*)d_in[11];
    const float* bw1   = (const float*)d_in[12];
    const float* bb1   = (const float*)d_in[13];
    const float* bw2   = (const float*)d_in[14];
    const float* bb2   = (const float*)d_in[15];
    const float* cw1   = (const float*)d_in[16];
    const float* cb1   = (const float*)d_in[17];
    const float* cw2   = (const float*)d_in[18];
    const float* cb2   = (const float*)d_in[19];
    float* out = (float*)d_out;
    char* ws = (char*)d_ws;

    _Float16* box_in   = (_Float16*)(ws + 278528);    // 2048x256
    _Float16* click_in = (_Float16*)(ws + 1327104);   // 2048x512
    _Float16* h_box    = (_Float16*)(ws + 3424256);   // 2048x768
    _Float16* h_click  = (_Float16*)(ws + 6569984);   // 2048x768
    _Float16* w1t_box  = (_Float16*)(ws + 9715712);   // 768x256
    _Float16* w2t_box  = (_Float16*)(ws + 10108928);  // 6144x768
    _Float16* w1t_clk  = (_Float16*)(ws + 19546112);  // 768x512
    _Float16* w2t_clk  = (_Float16*)(ws + 20332544);  // 6144x768

    // K1: everything with no inter-block dependency (one launch)
    mega_prep<<<4544, 256, 0, stream>>>(sem, boxc, boxq,
                                        bw1, cw1, w1t_box, w1t_clk,
                                        bw2, cw2, w2t_box, w2t_clk,
                                        propf, encf, encx, clkq,
                                        pcmin, pcmax, gB, boxm, clkm,
                                        box_in, click_in, out);
    // K2/K3: MLP GEMMs
    gemm_l1<<<dim3(16, 6, 2),  256, 0, stream>>>(box_in, click_in, w1t_box, w1t_clk,
                                                 bb1, cb1, h_box, h_click);
    gemm_l2<<<dim3(16, 48, 2), 256, 0, stream>>>(h_box, h_click, w2t_box, w2t_clk,
                                                 bb2, cb2, out);
}